// Round 1
// baseline (1346.156 us; speedup 1.0000x reference)
//
#include <hip/hip_runtime.h>
#include <math.h>

#define N_ROWS 32768
#define D 256
#define K 1024
#define DEPTH 3

#define MT 64     // rows per block
#define KT 128    // codes per chunk
#define DC 8      // k-step depth
#define MARGIN 0.05f

// ---- ws layout (bytes) ----
// 0        : idx[3][32768]  (393216)
// 393216   : counts[3][1024] int (12288)
// 405504   : flagcnt[3] int (12)
// 405516   : pad (4)
// 405520   : sse[3] double (24)
// 405544   : flaglist[32768] int (131072)
// 536616   : e2f[3][1024] float (12288)
// total ~549 KB

__global__ void e2_kernel(const float* __restrict__ cbs, float* __restrict__ e2f) {
    int gi = blockIdx.x * 256 + threadIdx.x;   // [0, 3072)
    const float* p = cbs + (size_t)gi * D;
    double s = 0.0;
    for (int k = 0; k < D; ++k) { double v = (double)p[k]; s = fma(v, v, s); }
    e2f[gi] = (float)s;
}

__global__ __launch_bounds__(256, 2) void argmin_kernel(
    const float* __restrict__ z, const float* __restrict__ qtot,
    const float* __restrict__ cb, const float* __restrict__ e2f,
    int* __restrict__ idxOut, int* __restrict__ flagcnt, int* __restrict__ flaglist)
{
    __shared__ __align__(16) float As[DC][MT];
    __shared__ __align__(16) float Bs[DC][KT];
    __shared__ __align__(16) float Ds[MT][KT];

    const int tid = threadIdx.x;
    const int tx = tid & 15;        // code group: codes tx*8 .. tx*8+7
    const int ty = tid >> 4;        // row group:  rows  ty*4 .. ty*4+3
    const int rowbase = blockIdx.x * MT;

    // scan ownership: each thread scans 32 codes of one row per chunk
    const int srow  = tid >> 2;     // 0..63
    const int spart = tid & 3;      // 0..3
    float bd1 = 3.4e38f, bd2 = 3.4e38f;
    int   bi1 = -1,      bi2 = -1;

    for (int ch = 0; ch < K / KT; ++ch) {
        const int cb0 = ch * KT;
        float acc[4][8];
        #pragma unroll
        for (int i = 0; i < 4; ++i)
            #pragma unroll
            for (int j = 0; j < 8; ++j) acc[i][j] = 0.0f;

        for (int s = 0; s < D / DC; ++s) {
            const int k0 = s * DC;
            __syncthreads();
            {   // stage A: 64 rows x 8 cols (residual = z - qtot)
                int r = tid >> 2;
                int c = (tid & 3) * 2;
                size_t off = (size_t)(rowbase + r) * D + k0 + c;
                float a0 = z[off]     - qtot[off];
                float a1 = z[off + 1] - qtot[off + 1];
                As[c][r] = a0; As[c + 1][r] = a1;
            }
            {   // stage B: 128 codes x 8 cols
                int code = tid >> 1;
                int c = (tid & 1) * 4;
                const float4 v = *(const float4*)(cb + (size_t)(cb0 + code) * D + k0 + c);
                Bs[c][code] = v.x; Bs[c + 1][code] = v.y;
                Bs[c + 2][code] = v.z; Bs[c + 3][code] = v.w;
            }
            __syncthreads();
            #pragma unroll
            for (int kk = 0; kk < DC; ++kk) {
                float a[4], b[8];
                #pragma unroll
                for (int i = 0; i < 4; ++i) a[i] = As[kk][ty * 4 + i];
                #pragma unroll
                for (int j = 0; j < 8; ++j) b[j] = Bs[kk][tx * 8 + j];
                #pragma unroll
                for (int i = 0; i < 4; ++i)
                    #pragma unroll
                    for (int j = 0; j < 8; ++j)
                        acc[i][j] = fmaf(a[i], b[j], acc[i][j]);
            }
        }
        __syncthreads();
        // epilogue: dist = e2 - 2*xe (x2 dropped; constant per row)
        #pragma unroll
        for (int i = 0; i < 4; ++i)
            #pragma unroll
            for (int j = 0; j < 8; ++j)
                Ds[ty * 4 + i][tx * 8 + j] = e2f[cb0 + tx * 8 + j] - 2.0f * acc[i][j];
        __syncthreads();
        // top-2 scan; visit order rotated for bank spread (tie-order safe: ties are
        // always flagged by the margin test and re-ranked exactly in refine_kernel)
        for (int i = 0; i < 32; ++i) {
            int cc = (i + srow + spart * 8) & 31;
            int c  = spart * 32 + cc;
            float dv = Ds[srow][c];
            int gi = cb0 + c;
            if (dv < bd1)      { bd2 = bd1; bi2 = bi1; bd1 = dv; bi1 = gi; }
            else if (dv < bd2) { bd2 = dv; bi2 = gi; }
        }
        __syncthreads();
    }

    // merge 4 parts per row (lexicographic: distance, then smaller index)
    float* fd = (float*)Ds;
    float* D1 = fd;        float* D2 = fd + 256;
    int*   I1 = (int*)(fd + 512); int* I2 = (int*)(fd + 768);
    D1[tid] = bd1; D2[tid] = bd2; I1[tid] = bi1; I2[tid] = bi2;
    __syncthreads();
    if (tid < MT) {
        float d1 = 3.4e38f, d2 = 3.4e38f; int i1 = -1, i2 = -1;
        for (int p = 0; p < 4; ++p) {
            int t = tid * 4 + p;
            float a1 = D1[t], a2 = D2[t]; int j1 = I1[t], j2 = I2[t];
            if (a1 < d1 || (a1 == d1 && j1 < i1)) { d2 = d1; i2 = i1; d1 = a1; i1 = j1; }
            else if (a1 < d2 || (a1 == d2 && j1 < i2)) { d2 = a1; i2 = j1; }
            if (a2 < d1 || (a2 == d1 && j2 < i1)) { d2 = d1; i2 = i1; d1 = a2; i1 = j2; }
            else if (a2 < d2 || (a2 == d2 && j2 < i2)) { d2 = a2; i2 = j2; }
        }
        int row = rowbase + tid;
        idxOut[row] = i1;
        if (d2 - d1 < MARGIN) {
            int pos = atomicAdd(flagcnt, 1);
            if (pos < N_ROWS) flaglist[pos] = row;
        }
    }
}

__global__ __launch_bounds__(256) void refine_kernel(
    const float* __restrict__ z, const float* __restrict__ qtot,
    const float* __restrict__ cb, int* __restrict__ idxOut,
    const int* __restrict__ flagcnt, const int* __restrict__ flaglist)
{
    __shared__ double rres[D];
    __shared__ double bd[256];
    __shared__ int    bidx[256];
    const int tid = threadIdx.x;
    int cnt = *flagcnt;
    if (cnt > N_ROWS) cnt = N_ROWS;
    for (int f = blockIdx.x; f < cnt; f += gridDim.x) {
        int row = flaglist[f];
        __syncthreads();
        rres[tid] = (double)z[(size_t)row * D + tid] - (double)qtot[(size_t)row * D + tid];
        __syncthreads();
        double best = 1e300; int bi = 0;
        for (int j = 0; j < 4; ++j) {
            int c = tid * 4 + j;
            const float* cp = cb + (size_t)c * D;
            double s = 0.0;
            for (int k = 0; k < D; ++k) {
                double df = rres[k] - (double)cp[k];
                s = fma(df, df, s);
            }
            if (s < best) { best = s; bi = c; }
        }
        bd[tid] = best; bidx[tid] = bi;
        __syncthreads();
        for (int off = 128; off > 0; off >>= 1) {
            if (tid < off) {
                if (bd[tid + off] < bd[tid] ||
                    (bd[tid + off] == bd[tid] && bidx[tid + off] < bidx[tid])) {
                    bd[tid] = bd[tid + off]; bidx[tid] = bidx[tid + off];
                }
            }
            __syncthreads();
        }
        if (tid == 0) idxOut[row] = bidx[0];
        __syncthreads();
    }
}

__global__ __launch_bounds__(256) void update_kernel(
    const float* __restrict__ z, float* __restrict__ qtot,
    const float* __restrict__ cb, const int* __restrict__ idxStage,
    int* __restrict__ counts, double* __restrict__ sse)
{
    int t = blockIdx.x * 256 + threadIdx.x;       // quad id, N_ROWS*64 total
    int row = t >> 6;
    int c4  = (t & 63) << 2;
    int idx = idxStage[row];
    size_t off = (size_t)row * D + c4;
    float4 cv = *(const float4*)(cb + (size_t)idx * D + c4);
    float4 qv = *(float4*)(qtot + off);
    qv.x += cv.x; qv.y += cv.y; qv.z += cv.z; qv.w += cv.w;
    *(float4*)(qtot + off) = qv;
    float4 zv = *(const float4*)(z + off);
    double dx = (double)(qv.x - zv.x), dy = (double)(qv.y - zv.y);
    double dz = (double)(qv.z - zv.z), dw = (double)(qv.w - zv.w);
    double s = dx * dx + dy * dy + dz * dz + dw * dw;
    for (int o = 32; o > 0; o >>= 1) s += __shfl_down(s, o, 64);
    __shared__ double wsum[4];
    int lane = threadIdx.x & 63, wv = threadIdx.x >> 6;
    if (lane == 0) wsum[wv] = s;
    __syncthreads();
    if (threadIdx.x == 0) {
        double tot = wsum[0] + wsum[1] + wsum[2] + wsum[3];
        atomicAdd(sse, tot);
    }
    if ((t & 63) == 0) atomicAdd(counts + idx, 1);
}

__global__ void compose_kernel(const int* __restrict__ idxAll, float* __restrict__ comp) {
    int n = blockIdx.x * 256 + threadIdx.x;
    if (n < N_ROWS) {
        int v = idxAll[n] + (idxAll[N_ROWS + n] << 10) + (idxAll[2 * N_ROWS + n] << 20);
        comp[n] = (float)v;
    }
}

__global__ void finalize_kernel(const int* __restrict__ counts, const double* __restrict__ sse,
                                float* __restrict__ loss, float* __restrict__ perps)
{
    __shared__ double red[16];
    const int tid = threadIdx.x;   // 1024 threads
    for (int d = 0; d < DEPTH; ++d) {
        double p = (double)counts[d * K + tid] / 32768.0;
        double s = p * log(p + 1e-10);
        for (int o = 32; o > 0; o >>= 1) s += __shfl_down(s, o, 64);
        if ((tid & 63) == 0) red[tid >> 6] = s;
        __syncthreads();
        if (tid == 0) {
            double tot = 0.0;
            for (int i = 0; i < 16; ++i) tot += red[i];
            perps[d] = (float)exp(-tot);
        }
        __syncthreads();
    }
    if (tid == 0)
        loss[0] = (float)(1.25 * (sse[0] + sse[1] + sse[2]) / 8388608.0);
}

extern "C" void kernel_launch(void* const* d_in, const int* in_sizes, int n_in,
                              void* d_out, int out_size, void* d_ws, size_t ws_size,
                              hipStream_t stream)
{
    const float* z   = (const float*)d_in[0];
    const float* cbs = (const float*)d_in[1];
    float* out = (float*)d_out;
    char*  ws  = (char*)d_ws;

    int*    idxAll   = (int*)ws;
    int*    counts   = (int*)(ws + 393216);
    int*    flagcnt  = (int*)(ws + 405504);
    double* sse      = (double*)(ws + 405520);
    int*    flaglist = (int*)(ws + 405544);
    float*  e2f      = (float*)(ws + 536616);

    float* qtot  = out;                       // 8388608 elems
    float* loss  = out + 8388608;             // 1
    float* comp  = out + 8388609;             // 32768
    float* perps = out + 8388609 + 32768;     // 3

    hipMemsetAsync(d_out, 0, (size_t)out_size * 4, stream);
    hipMemsetAsync(ws + 393216, 0, 405544 - 393216, stream);

    e2_kernel<<<12, 256, 0, stream>>>(cbs, e2f);

    for (int d = 0; d < DEPTH; ++d) {
        const float* cb = cbs + (size_t)d * K * D;
        argmin_kernel<<<N_ROWS / MT, 256, 0, stream>>>(
            z, qtot, cb, e2f + d * K, idxAll + d * N_ROWS, flagcnt + d, flaglist);
        refine_kernel<<<128, 256, 0, stream>>>(
            z, qtot, cb, idxAll + d * N_ROWS, flagcnt + d, flaglist);
        update_kernel<<<N_ROWS * 64 / 256, 256, 0, stream>>>(
            z, qtot, cb, idxAll + d * N_ROWS, counts + d * K, sse + d);
    }

    compose_kernel<<<(N_ROWS + 255) / 256, 256, 0, stream>>>(idxAll, comp);
    finalize_kernel<<<1, 1024, 0, stream>>>(counts, sse, loss, perps);
}

// Round 2
// 807.338 us; speedup vs baseline: 1.6674x; 1.6674x over previous
//
#include <hip/hip_runtime.h>
#include <math.h>

#define N_ROWS 32768
#define D 256
#define K 1024
#define DEPTH 3
#define MARGIN 0.05f

typedef __bf16 bf16x8 __attribute__((ext_vector_type(8)));
typedef float f32x4 __attribute__((ext_vector_type(4)));

// ---- ws layout (bytes) ----
// 0        : idxAll[3][32768] int          (393216)
// 393216   : counts[3][1024] int           (12288)   -> 405504
// 405504   : flagcnt[3] int                (12, pad->405520)
// 405520   : sse[3] double                 (24) -> 405544, pad -> 405568
// 405568   : flaglist[32768] int           (131072) -> 536640
// 536640   : e2f[3][1024] float            (12288)  -> 548928
// 548928   : cb_packed bf16 [3][1024][512] (3145728) -> 3694656
// 3694656  : r_packed bf16 [32768][512]    (33554432) -> 37249088
// 37249088 : partials float4 [16][32768]   (8388608) -> 45637696  (~43.6 MB)

__device__ __forceinline__ void gload_lds16(const void* g, void* l) {
    __builtin_amdgcn_global_load_lds(
        (const __attribute__((address_space(1))) void*)g,
        (__attribute__((address_space(3))) void*)l, 16, 0, 0);
}

__device__ __forceinline__ unsigned short f2bf(float f) {
    unsigned u = __float_as_uint(f);
    return (unsigned short)((u + 0x7fffu + ((u >> 16) & 1u)) >> 16);
}

__global__ void e2_kernel(const float* __restrict__ cbs, float* __restrict__ e2f) {
    int gi = blockIdx.x * 256 + threadIdx.x;   // [0, 3072)
    const float* p = cbs + (size_t)gi * D;
    double s = 0.0;
    for (int k = 0; k < D; ++k) { double v = (double)p[k]; s = fma(v, v, s); }
    e2f[gi] = (float)s;
}

// Pack fp32 rows (optionally minus sub) into [hi(256)|lo(256)] bf16 rows.
__global__ __launch_bounds__(256) void pack_kernel(
    const float* __restrict__ src, const float* __restrict__ sub,
    unsigned short* __restrict__ dst, int useSub)
{
    int t = blockIdx.x * 256 + threadIdx.x;
    int row = t >> 5;
    int k8 = (t & 31) * 8;
    size_t off = (size_t)row * D + k8;
    float4 v0 = *(const float4*)(src + off);
    float4 v1 = *(const float4*)(src + off + 4);
    if (useSub) {
        float4 q0 = *(const float4*)(sub + off);
        float4 q1 = *(const float4*)(sub + off + 4);
        v0.x -= q0.x; v0.y -= q0.y; v0.z -= q0.z; v0.w -= q0.w;
        v1.x -= q1.x; v1.y -= q1.y; v1.z -= q1.z; v1.w -= q1.w;
    }
    float v[8] = {v0.x, v0.y, v0.z, v0.w, v1.x, v1.y, v1.z, v1.w};
    ushort hi[8], lo[8];
    #pragma unroll
    for (int j = 0; j < 8; ++j) {
        ushort h = f2bf(v[j]);
        hi[j] = h;
        float hf = __uint_as_float(((unsigned)h) << 16);
        lo[j] = f2bf(v[j] - hf);
    }
    typedef __attribute__((ext_vector_type(8))) unsigned short u16x8;
    u16x8 hv, lv;
    #pragma unroll
    for (int j = 0; j < 8; ++j) { hv[j] = hi[j]; lv[j] = lo[j]; }
    *(u16x8*)(dst + (size_t)row * 512 + k8) = hv;
    *(u16x8*)(dst + (size_t)row * 512 + 256 + k8) = lv;
}

// dist[code][row] partial top-2 via MFMA. A = codebook (M=codes), B = rows (N).
// Swapped so the code (reduction) axis is lane-local in C.
__global__ __launch_bounds__(256, 2) void mfma_argmin_kernel(
    const unsigned short* __restrict__ cbp,   // [1024][512] packed bf16
    const unsigned short* __restrict__ rp,    // [32768][512] packed bf16
    const float* __restrict__ e2f,            // [1024]
    float4* __restrict__ partials)            // [16][32768]
{
    __shared__ __align__(16) __bf16 Asm[128 * 64];
    __shared__ __align__(16) __bf16 Bsm[128 * 64];
    __shared__ float e2s[128];

    const int tid = threadIdx.x;
    const int lane = tid & 63;
    const int w = tid >> 6;
    const int wm = w >> 1, wn = w & 1;
    const int cc = blockIdx.x & 7;
    const int rc = blockIdx.x >> 3;
    const int cb0 = cc * 128;
    const int row0 = rc * 128;

    if (tid < 128) e2s[tid] = e2f[cb0 + tid];

    const unsigned short* aG[4];
    const unsigned short* bG[4];
    __bf16* aL[4];
    __bf16* bL[4];
    #pragma unroll
    for (int t = 0; t < 4; ++t) {
        int q = w * 4 + t;                 // 1KB chunk id (wave-uniform)
        int r8 = q * 8 + (lane >> 3);      // row within tile
        int kofs = (lane & 7) * 8;         // bf16 elems within 128B row
        aG[t] = cbp + (size_t)(cb0 + r8) * 512 + kofs;
        bG[t] = rp  + (size_t)(row0 + r8) * 512 + kofs;
        aL[t] = Asm + q * 512;             // 512 elems = 1024 B
        bL[t] = Bsm + q * 512;
    }

    f32x4 acc[4][4];
    #pragma unroll
    for (int m = 0; m < 4; ++m)
        #pragma unroll
        for (int n = 0; n < 4; ++n)
            acc[m][n] = (f32x4){0.f, 0.f, 0.f, 0.f};

    // K=768 three-term split: A windows hi,lo,hi ; B windows hi,hi,lo
    constexpr int aO[12] = {0,64,128,192, 256,320,384,448, 0,64,128,192};
    constexpr int bO[12] = {0,64,128,192, 0,64,128,192, 256,320,384,448};

    #pragma unroll
    for (int s = 0; s < 12; ++s) {
        __syncthreads();                   // prior reads done before overwrite
        #pragma unroll
        for (int t = 0; t < 4; ++t) {
            gload_lds16(aG[t] + aO[s], aL[t]);
            gload_lds16(bG[t] + bO[s], bL[t]);
        }
        __syncthreads();                   // drains vmcnt(0): tile visible
        #pragma unroll
        for (int kk = 0; kk < 2; ++kk) {
            bf16x8 af[4], bfr[4];
            #pragma unroll
            for (int m = 0; m < 4; ++m) {
                int cl = wm * 64 + m * 16 + (lane & 15);
                af[m] = *(const bf16x8*)(Asm + cl * 64 + kk * 32 + (lane >> 4) * 8);
            }
            #pragma unroll
            for (int n = 0; n < 4; ++n) {
                int rl = wn * 64 + n * 16 + (lane & 15);
                bfr[n] = *(const bf16x8*)(Bsm + rl * 64 + kk * 32 + (lane >> 4) * 8);
            }
            #pragma unroll
            for (int m = 0; m < 4; ++m)
                #pragma unroll
                for (int n = 0; n < 4; ++n)
                    acc[m][n] = __builtin_amdgcn_mfma_f32_16x16x32_bf16(
                        af[m], bfr[n], acc[m][n], 0, 0, 0);
        }
    }

    // epilogue: dist = e2 - 2*dot ; per-lane top-2 over 16 in-register codes,
    // then butterfly over lane^16, lane^32 (code groups).
    float e2v[4][4];
    #pragma unroll
    for (int m = 0; m < 4; ++m)
        #pragma unroll
        for (int r = 0; r < 4; ++r)
            e2v[m][r] = e2s[wm * 64 + m * 16 + (lane >> 4) * 4 + r];

    #pragma unroll
    for (int n = 0; n < 4; ++n) {
        float d1 = 3.4e38f, d2 = 3.4e38f;
        int i1 = 0x7fffffff, i2 = 0x7fffffff;
        #pragma unroll
        for (int m = 0; m < 4; ++m)
            #pragma unroll
            for (int r = 0; r < 4; ++r) {
                float dv = e2v[m][r] - 2.0f * acc[m][n][r];
                int c = cb0 + wm * 64 + m * 16 + (lane >> 4) * 4 + r;
                if (dv < d1)      { d2 = d1; i2 = i1; d1 = dv; i1 = c; }
                else if (dv < d2) { d2 = dv; i2 = c; }
            }
        #pragma unroll
        for (int mk = 0; mk < 2; ++mk) {
            int mask = mk ? 32 : 16;
            float od1 = __shfl_xor(d1, mask, 64);
            float od2 = __shfl_xor(d2, mask, 64);
            int   oi1 = __shfl_xor(i1, mask, 64);
            int   oi2 = __shfl_xor(i2, mask, 64);
            if (od1 < d1 || (od1 == d1 && oi1 < i1)) { d2 = d1; i2 = i1; d1 = od1; i1 = oi1; }
            else if (od1 < d2 || (od1 == d2 && oi1 < i2)) { d2 = od1; i2 = oi1; }
            if (od2 < d1 || (od2 == d1 && oi2 < i1)) { d2 = d1; i2 = i1; d1 = od2; i1 = oi2; }
            else if (od2 < d2 || (od2 == d2 && oi2 < i2)) { d2 = od2; i2 = oi2; }
        }
        if (lane < 16) {
            int row = row0 + wn * 64 + n * 16 + lane;
            float4 o;
            o.x = d1; o.y = d2;
            o.z = __int_as_float(i1); o.w = __int_as_float(i2);
            partials[(size_t)(cc * 2 + wm) * N_ROWS + row] = o;
        }
    }
}

__global__ __launch_bounds__(256) void merge_kernel(
    const float4* __restrict__ partials, int* __restrict__ idxOut,
    int* __restrict__ flagcnt, int* __restrict__ flaglist)
{
    int row = blockIdx.x * 256 + threadIdx.x;
    float d1 = 3.4e38f, d2 = 3.4e38f;
    int i1 = 0x7fffffff, i2 = 0x7fffffff;
    #pragma unroll 4
    for (int pc = 0; pc < 16; ++pc) {
        float4 p = partials[(size_t)pc * N_ROWS + row];
        float pd1 = p.x, pd2 = p.y;
        int   pi1 = __float_as_int(p.z), pi2 = __float_as_int(p.w);
        if (pd1 < d1 || (pd1 == d1 && pi1 < i1)) { d2 = d1; i2 = i1; d1 = pd1; i1 = pi1; }
        else if (pd1 < d2 || (pd1 == d2 && pi1 < i2)) { d2 = pd1; i2 = pi1; }
        if (pd2 < d1 || (pd2 == d1 && pi2 < i1)) { d2 = d1; i2 = i1; d1 = pd2; i1 = pi2; }
        else if (pd2 < d2 || (pd2 == d2 && pi2 < i2)) { d2 = pd2; i2 = pi2; }
    }
    idxOut[row] = i1;
    if (d2 - d1 < MARGIN) {
        int pos = atomicAdd(flagcnt, 1);
        if (pos < N_ROWS) flaglist[pos] = row;
    }
}

__global__ __launch_bounds__(256) void refine_kernel(
    const float* __restrict__ z, const float* __restrict__ qtot,
    const float* __restrict__ cb, int* __restrict__ idxOut,
    const int* __restrict__ flagcnt, const int* __restrict__ flaglist)
{
    __shared__ double rres[D];
    __shared__ double bd[256];
    __shared__ int    bidx[256];
    const int tid = threadIdx.x;
    int cnt = *flagcnt;
    if (cnt > N_ROWS) cnt = N_ROWS;
    for (int f = blockIdx.x; f < cnt; f += gridDim.x) {
        int row = flaglist[f];
        __syncthreads();
        rres[tid] = (double)z[(size_t)row * D + tid] - (double)qtot[(size_t)row * D + tid];
        __syncthreads();
        double best = 1e300; int bi = 0;
        for (int j = 0; j < 4; ++j) {
            int c = tid * 4 + j;
            const float* cp = cb + (size_t)c * D;
            double s = 0.0;
            for (int k = 0; k < D; ++k) {
                double df = rres[k] - (double)cp[k];
                s = fma(df, df, s);
            }
            if (s < best) { best = s; bi = c; }
        }
        bd[tid] = best; bidx[tid] = bi;
        __syncthreads();
        for (int off = 128; off > 0; off >>= 1) {
            if (tid < off) {
                if (bd[tid + off] < bd[tid] ||
                    (bd[tid + off] == bd[tid] && bidx[tid + off] < bidx[tid])) {
                    bd[tid] = bd[tid + off]; bidx[tid] = bidx[tid + off];
                }
            }
            __syncthreads();
        }
        if (tid == 0) idxOut[row] = bidx[0];
        __syncthreads();
    }
}

__global__ __launch_bounds__(256) void update_kernel(
    const float* __restrict__ z, float* __restrict__ qtot,
    const float* __restrict__ cb, const int* __restrict__ idxStage,
    int* __restrict__ counts, double* __restrict__ sse)
{
    int t = blockIdx.x * 256 + threadIdx.x;       // quad id
    int row = t >> 6;
    int c4  = (t & 63) << 2;
    int idx = idxStage[row];
    size_t off = (size_t)row * D + c4;
    float4 cv = *(const float4*)(cb + (size_t)idx * D + c4);
    float4 qv = *(float4*)(qtot + off);
    qv.x += cv.x; qv.y += cv.y; qv.z += cv.z; qv.w += cv.w;
    *(float4*)(qtot + off) = qv;
    float4 zv = *(const float4*)(z + off);
    double dx = (double)(qv.x - zv.x), dy = (double)(qv.y - zv.y);
    double dz = (double)(qv.z - zv.z), dw = (double)(qv.w - zv.w);
    double s = dx * dx + dy * dy + dz * dz + dw * dw;
    for (int o = 32; o > 0; o >>= 1) s += __shfl_down(s, o, 64);
    __shared__ double wsum[4];
    int lane = threadIdx.x & 63, wv = threadIdx.x >> 6;
    if (lane == 0) wsum[wv] = s;
    __syncthreads();
    if (threadIdx.x == 0) {
        double tot = wsum[0] + wsum[1] + wsum[2] + wsum[3];
        atomicAdd(sse, tot);
    }
    if ((t & 63) == 0) atomicAdd(counts + idx, 1);
}

__global__ void compose_kernel(const int* __restrict__ idxAll, float* __restrict__ comp) {
    int n = blockIdx.x * 256 + threadIdx.x;
    if (n < N_ROWS) {
        int v = idxAll[n] + (idxAll[N_ROWS + n] << 10) + (idxAll[2 * N_ROWS + n] << 20);
        comp[n] = (float)v;
    }
}

__global__ void finalize_kernel(const int* __restrict__ counts, const double* __restrict__ sse,
                                float* __restrict__ loss, float* __restrict__ perps)
{
    __shared__ double red[16];
    const int tid = threadIdx.x;   // 1024 threads
    for (int d = 0; d < DEPTH; ++d) {
        double p = (double)counts[d * K + tid] / 32768.0;
        double s = p * log(p + 1e-10);
        for (int o = 32; o > 0; o >>= 1) s += __shfl_down(s, o, 64);
        if ((tid & 63) == 0) red[tid >> 6] = s;
        __syncthreads();
        if (tid == 0) {
            double tot = 0.0;
            for (int i = 0; i < 16; ++i) tot += red[i];
            perps[d] = (float)exp(-tot);
        }
        __syncthreads();
    }
    if (tid == 0)
        loss[0] = (float)(1.25 * (sse[0] + sse[1] + sse[2]) / 8388608.0);
}

extern "C" void kernel_launch(void* const* d_in, const int* in_sizes, int n_in,
                              void* d_out, int out_size, void* d_ws, size_t ws_size,
                              hipStream_t stream)
{
    const float* z   = (const float*)d_in[0];
    const float* cbs = (const float*)d_in[1];
    float* out = (float*)d_out;
    char*  ws  = (char*)d_ws;

    int*            idxAll   = (int*)ws;
    int*            counts   = (int*)(ws + 393216);
    int*            flagcnt  = (int*)(ws + 405504);
    double*         sse      = (double*)(ws + 405520);
    int*            flaglist = (int*)(ws + 405568);
    float*          e2f      = (float*)(ws + 536640);
    unsigned short* cbp      = (unsigned short*)(ws + 548928);
    unsigned short* rp       = (unsigned short*)(ws + 3694656);
    float4*         partials = (float4*)(ws + 37249088);

    float* qtot  = out;                       // 8388608 elems
    float* loss  = out + 8388608;             // 1
    float* comp  = out + 8388609;             // 32768
    float* perps = out + 8388609 + 32768;     // 3

    hipMemsetAsync(d_out, 0, (size_t)out_size * 4, stream);
    hipMemsetAsync(ws + 393216, 0, 405568 - 393216, stream);

    e2_kernel<<<12, 256, 0, stream>>>(cbs, e2f);
    pack_kernel<<<(3072 * 32) / 256, 256, 0, stream>>>(cbs, nullptr, cbp, 0);

    for (int d = 0; d < DEPTH; ++d) {
        const float* cb = cbs + (size_t)d * K * D;
        pack_kernel<<<(N_ROWS * 32) / 256, 256, 0, stream>>>(z, qtot, rp, d > 0 ? 1 : 0);
        mfma_argmin_kernel<<<2048, 256, 0, stream>>>(
            cbp + (size_t)d * K * 512, rp, e2f + d * K, partials);
        merge_kernel<<<N_ROWS / 256, 256, 0, stream>>>(
            partials, idxAll + d * N_ROWS, flagcnt + d, flaglist);
        refine_kernel<<<128, 256, 0, stream>>>(
            z, qtot, cb, idxAll + d * N_ROWS, flagcnt + d, flaglist);
        update_kernel<<<N_ROWS * 64 / 256, 256, 0, stream>>>(
            z, qtot, cb, idxAll + d * N_ROWS, counts + d * K, sse + d);
    }

    compose_kernel<<<(N_ROWS + 255) / 256, 256, 0, stream>>>(idxAll, comp);
    finalize_kernel<<<1, 1024, 0, stream>>>(counts, sse, loss, perps);
}

// Round 3
// 538.202 us; speedup vs baseline: 2.5012x; 1.5001x over previous
//
#include <hip/hip_runtime.h>
#include <math.h>

#define N_ROWS 32768
#define D 256
#define K 1024
#define DEPTH 3
#define MARGIN 0.05f

typedef __bf16 bf16x8 __attribute__((ext_vector_type(8)));
typedef float f32x4 __attribute__((ext_vector_type(4)));

// ---- ws layout (bytes) ----
// 0        idxAll[3][32768] int        -> 393216
// 393216   counts[3][1024] int         -> 405504
// 405504   flagcnt[3] int (pad to 405520)
// 405520   flaglist[32768] int         -> 536592
// 536592   ssepart[3][2048] double     -> 585744
// 585744   e2f[3][1024] float          -> 598032 (pad to 598080)
// 598080   cbp bf16 [3][1024][512]     -> 3743808
// 3743808  rp  bf16 [32768][512]       -> 37298240
// 37298240 partials float4 [16][32768] -> 45686848  (~45.7 MB, same as R2's proven 45.6)

__device__ __forceinline__ void gload_lds16(const void* g, void* l) {
    __builtin_amdgcn_global_load_lds(
        (const __attribute__((address_space(1))) void*)g,
        (__attribute__((address_space(3))) void*)l, 16, 0, 0);
}

__device__ __forceinline__ unsigned short f2bf(float f) {
    unsigned u = __float_as_uint(f);
    return (unsigned short)((u + 0x7fffu + ((u >> 16) & 1u)) >> 16);
}

__global__ void e2_kernel(const float* __restrict__ cbs, float* __restrict__ e2f) {
    int gi = blockIdx.x * 256 + threadIdx.x;   // [0, 3072)
    const float* p = cbs + (size_t)gi * D;
    double s = 0.0;
    for (int k = 0; k < D; ++k) { double v = (double)p[k]; s = fma(v, v, s); }
    e2f[gi] = (float)s;
}

// Pack fp32 rows into [hi(256)|lo(256)] bf16 rows (stage-0 z pack and codebooks).
__global__ __launch_bounds__(256) void pack_kernel(
    const float* __restrict__ src, unsigned short* __restrict__ dst)
{
    int t = blockIdx.x * 256 + threadIdx.x;
    int row = t >> 5;
    int k8 = (t & 31) * 8;
    size_t off = (size_t)row * D + k8;
    float4 v0 = *(const float4*)(src + off);
    float4 v1 = *(const float4*)(src + off + 4);
    float v[8] = {v0.x, v0.y, v0.z, v0.w, v1.x, v1.y, v1.z, v1.w};
    typedef __attribute__((ext_vector_type(8))) unsigned short u16x8;
    u16x8 hv, lv;
    #pragma unroll
    for (int j = 0; j < 8; ++j) {
        ushort h = f2bf(v[j]);
        hv[j] = h;
        float hf = __uint_as_float(((unsigned)h) << 16);
        lv[j] = f2bf(v[j] - hf);
    }
    *(u16x8*)(dst + (size_t)row * 512 + k8) = hv;
    *(u16x8*)(dst + (size_t)row * 512 + 256 + k8) = lv;
}

// dist[code][row] partial top-2 via MFMA. A = codebook (M=codes), B = rows (N).
__global__ __launch_bounds__(256, 2) void mfma_argmin_kernel(
    const unsigned short* __restrict__ cbp,   // [1024][512] packed bf16
    const unsigned short* __restrict__ rp,    // [32768][512] packed bf16
    const float* __restrict__ e2f,            // [1024]
    float4* __restrict__ partials)            // [16][32768]
{
    __shared__ __align__(16) __bf16 Asm[128 * 64];
    __shared__ __align__(16) __bf16 Bsm[128 * 64];
    __shared__ float e2s[128];

    const int tid = threadIdx.x;
    const int lane = tid & 63;
    const int w = tid >> 6;
    const int wm = w >> 1, wn = w & 1;
    const int cc = blockIdx.x & 7;
    const int rc = blockIdx.x >> 3;
    const int cb0 = cc * 128;
    const int row0 = rc * 128;

    if (tid < 128) e2s[tid] = e2f[cb0 + tid];

    const unsigned short* aG[4];
    const unsigned short* bG[4];
    __bf16* aL[4];
    __bf16* bL[4];
    #pragma unroll
    for (int t = 0; t < 4; ++t) {
        int q = w * 4 + t;
        int r8 = q * 8 + (lane >> 3);
        int kofs = (lane & 7) * 8;
        aG[t] = cbp + (size_t)(cb0 + r8) * 512 + kofs;
        bG[t] = rp  + (size_t)(row0 + r8) * 512 + kofs;
        aL[t] = Asm + q * 512;
        bL[t] = Bsm + q * 512;
    }

    f32x4 acc[4][4];
    #pragma unroll
    for (int m = 0; m < 4; ++m)
        #pragma unroll
        for (int n = 0; n < 4; ++n)
            acc[m][n] = (f32x4){0.f, 0.f, 0.f, 0.f};

    constexpr int aO[12] = {0,64,128,192, 256,320,384,448, 0,64,128,192};
    constexpr int bO[12] = {0,64,128,192, 0,64,128,192, 256,320,384,448};

    #pragma unroll
    for (int s = 0; s < 12; ++s) {
        __syncthreads();
        #pragma unroll
        for (int t = 0; t < 4; ++t) {
            gload_lds16(aG[t] + aO[s], aL[t]);
            gload_lds16(bG[t] + bO[s], bL[t]);
        }
        __syncthreads();
        #pragma unroll
        for (int kk = 0; kk < 2; ++kk) {
            bf16x8 af[4], bfr[4];
            #pragma unroll
            for (int m = 0; m < 4; ++m) {
                int cl = wm * 64 + m * 16 + (lane & 15);
                af[m] = *(const bf16x8*)(Asm + cl * 64 + kk * 32 + (lane >> 4) * 8);
            }
            #pragma unroll
            for (int n = 0; n < 4; ++n) {
                int rl = wn * 64 + n * 16 + (lane & 15);
                bfr[n] = *(const bf16x8*)(Bsm + rl * 64 + kk * 32 + (lane >> 4) * 8);
            }
            #pragma unroll
            for (int m = 0; m < 4; ++m)
                #pragma unroll
                for (int n = 0; n < 4; ++n)
                    acc[m][n] = __builtin_amdgcn_mfma_f32_16x16x32_bf16(
                        af[m], bfr[n], acc[m][n], 0, 0, 0);
        }
    }

    float e2v[4][4];
    #pragma unroll
    for (int m = 0; m < 4; ++m)
        #pragma unroll
        for (int r = 0; r < 4; ++r)
            e2v[m][r] = e2s[wm * 64 + m * 16 + (lane >> 4) * 4 + r];

    #pragma unroll
    for (int n = 0; n < 4; ++n) {
        float d1 = 3.4e38f, d2 = 3.4e38f;
        int i1 = 0x7fffffff, i2 = 0x7fffffff;
        #pragma unroll
        for (int m = 0; m < 4; ++m)
            #pragma unroll
            for (int r = 0; r < 4; ++r) {
                float dv = e2v[m][r] - 2.0f * acc[m][n][r];
                int c = cb0 + wm * 64 + m * 16 + (lane >> 4) * 4 + r;
                if (dv < d1)      { d2 = d1; i2 = i1; d1 = dv; i1 = c; }
                else if (dv < d2) { d2 = dv; i2 = c; }
            }
        #pragma unroll
        for (int mk = 0; mk < 2; ++mk) {
            int mask = mk ? 32 : 16;
            float od1 = __shfl_xor(d1, mask, 64);
            float od2 = __shfl_xor(d2, mask, 64);
            int   oi1 = __shfl_xor(i1, mask, 64);
            int   oi2 = __shfl_xor(i2, mask, 64);
            if (od1 < d1 || (od1 == d1 && oi1 < i1)) { d2 = d1; i2 = i1; d1 = od1; i1 = oi1; }
            else if (od1 < d2 || (od1 == d2 && oi1 < i2)) { d2 = od1; i2 = oi1; }
            if (od2 < d1 || (od2 == d1 && oi2 < i1)) { d2 = d1; i2 = i1; d1 = od2; i1 = oi2; }
            else if (od2 < d2 || (od2 == d2 && oi2 < i2)) { d2 = od2; i2 = oi2; }
        }
        if (lane < 16) {
            int row = row0 + wn * 64 + n * 16 + lane;
            float4 o;
            o.x = d1; o.y = d2;
            o.z = __int_as_float(i1); o.w = __int_as_float(i2);
            partials[(size_t)(cc * 2 + wm) * N_ROWS + row] = o;
        }
    }
}

__global__ __launch_bounds__(256) void merge_kernel(
    const float4* __restrict__ partials, int* __restrict__ idxOut,
    int* __restrict__ flagcnt, int* __restrict__ flaglist)
{
    int row = blockIdx.x * 256 + threadIdx.x;
    float d1 = 3.4e38f, d2 = 3.4e38f;
    int i1 = 0x7fffffff, i2 = 0x7fffffff;
    #pragma unroll 4
    for (int pc = 0; pc < 16; ++pc) {
        float4 p = partials[(size_t)pc * N_ROWS + row];
        float pd1 = p.x, pd2 = p.y;
        int   pi1 = __float_as_int(p.z), pi2 = __float_as_int(p.w);
        if (pd1 < d1 || (pd1 == d1 && pi1 < i1)) { d2 = d1; i2 = i1; d1 = pd1; i1 = pi1; }
        else if (pd1 < d2 || (pd1 == d2 && pi1 < i2)) { d2 = pd1; i2 = pi1; }
        if (pd2 < d1 || (pd2 == d1 && pi2 < i1)) { d2 = d1; i2 = i1; d1 = pd2; i1 = pi2; }
        else if (pd2 < d2 || (pd2 == d2 && pi2 < i2)) { d2 = pd2; i2 = pi2; }
    }
    idxOut[row] = i1;
    if (d2 - d1 < MARGIN) {
        int pos = atomicAdd(flagcnt, 1);
        if (pos < N_ROWS) flaglist[pos] = row;
    }
}

// Exact fp64 re-rank for near-tie rows. residual = z - (useQ ? qtot : 0).
__global__ __launch_bounds__(256) void refine_kernel(
    const float* __restrict__ z, const float* __restrict__ qtot,
    const float* __restrict__ cb, int* __restrict__ idxOut,
    const int* __restrict__ flagcnt, const int* __restrict__ flaglist, int useQ)
{
    __shared__ double rres[D];
    __shared__ double bd[256];
    __shared__ int    bidx[256];
    const int tid = threadIdx.x;
    int cnt = *flagcnt;
    if (cnt > N_ROWS) cnt = N_ROWS;
    for (int f = blockIdx.x; f < cnt; f += gridDim.x) {
        int row = flaglist[f];
        __syncthreads();
        {
            float zv = z[(size_t)row * D + tid];
            float qv = useQ ? qtot[(size_t)row * D + tid] : 0.0f;
            // match reference fp32 residual exactly, then go fp64
            rres[tid] = (double)(zv - qv);
        }
        __syncthreads();
        double best = 1e300; int bi = 0;
        for (int j = 0; j < 4; ++j) {
            int c = tid * 4 + j;
            const float* cp = cb + (size_t)c * D;
            double s = 0.0;
            for (int k = 0; k < D; ++k) {
                double df = rres[k] - (double)cp[k];
                s = fma(df, df, s);
            }
            if (s < best) { best = s; bi = c; }
        }
        bd[tid] = best; bidx[tid] = bi;
        __syncthreads();
        for (int off = 128; off > 0; off >>= 1) {
            if (tid < off) {
                if (bd[tid + off] < bd[tid] ||
                    (bd[tid + off] == bd[tid] && bidx[tid + off] < bidx[tid])) {
                    bd[tid] = bd[tid + off]; bidx[tid] = bidx[tid + off];
                }
            }
            __syncthreads();
        }
        if (tid == 0) idxOut[row] = bidx[0];
        __syncthreads();
    }
}

// Fused: qtot += cb[idx]; residual = z - qtot; pack residual (optional);
// SSE partial per block; counts. One pass over memory.
__global__ __launch_bounds__(256) void fused_update_kernel(
    const float* __restrict__ z, float* __restrict__ qtot,
    const float* __restrict__ cb, const int* __restrict__ idxStage,
    unsigned short* __restrict__ rpOut, int* __restrict__ counts,
    double* __restrict__ ssepart, int writeRp, int firstStage)
{
    double s = 0.0;
    const int base = blockIdx.x * 256 + threadIdx.x;
    #pragma unroll
    for (int it = 0; it < 4; ++it) {
        int t = base + it * 524288;            // quad id over N_ROWS*64
        int row = t >> 6;
        int c4  = (t & 63) << 2;
        int idx = idxStage[row];
        size_t off = (size_t)row * D + c4;
        float4 cv = *(const float4*)(cb + (size_t)idx * D + c4);
        float4 qv;
        if (firstStage) {
            qv = cv;
        } else {
            qv = *(const float4*)(qtot + off);
            qv.x += cv.x; qv.y += cv.y; qv.z += cv.z; qv.w += cv.w;
        }
        *(float4*)(qtot + off) = qv;
        float4 zv = *(const float4*)(z + off);
        float r0 = zv.x - qv.x, r1 = zv.y - qv.y;
        float r2 = zv.z - qv.z, r3 = zv.w - qv.w;
        s = fma((double)r0, (double)r0, s);
        s = fma((double)r1, (double)r1, s);
        s = fma((double)r2, (double)r2, s);
        s = fma((double)r3, (double)r3, s);
        if (writeRp) {
            float rv[4] = {r0, r1, r2, r3};
            ushort4 hv, lv;
            ushort* hp = (ushort*)&hv; ushort* lp = (ushort*)&lv;
            #pragma unroll
            for (int j = 0; j < 4; ++j) {
                ushort h = f2bf(rv[j]);
                hp[j] = h;
                float hf = __uint_as_float(((unsigned)h) << 16);
                lp[j] = f2bf(rv[j] - hf);
            }
            *(ushort4*)(rpOut + (size_t)row * 512 + c4) = hv;
            *(ushort4*)(rpOut + (size_t)row * 512 + 256 + c4) = lv;
        }
        if ((t & 63) == 0) atomicAdd(counts + idx, 1);
    }
    // block-level SSE reduction -> ssepart[blockIdx.x]
    for (int o = 32; o > 0; o >>= 1) s += __shfl_down(s, o, 64);
    __shared__ double wsum[4];
    int lane = threadIdx.x & 63, wv = threadIdx.x >> 6;
    if (lane == 0) wsum[wv] = s;
    __syncthreads();
    if (threadIdx.x == 0)
        ssepart[blockIdx.x] = wsum[0] + wsum[1] + wsum[2] + wsum[3];
}

__global__ void compose_kernel(const int* __restrict__ idxAll, float* __restrict__ comp) {
    int n = blockIdx.x * 256 + threadIdx.x;
    if (n < N_ROWS) {
        int v = idxAll[n] + (idxAll[N_ROWS + n] << 10) + (idxAll[2 * N_ROWS + n] << 20);
        comp[n] = (float)v;
    }
}

__global__ void finalize_kernel(const int* __restrict__ counts, const double* __restrict__ ssepart,
                                float* __restrict__ loss, float* __restrict__ perps)
{
    __shared__ double red[16];
    __shared__ double lossAcc;
    const int tid = threadIdx.x;   // 1024 threads
    if (tid == 0) lossAcc = 0.0;
    __syncthreads();
    for (int d = 0; d < DEPTH; ++d) {
        double p = (double)counts[d * K + tid] / 32768.0;
        double s = p * log(p + 1e-10);
        double q = ssepart[d * 2048 + tid] + ssepart[d * 2048 + 1024 + tid];
        for (int o = 32; o > 0; o >>= 1) {
            s += __shfl_down(s, o, 64);
            q += __shfl_down(q, o, 64);
        }
        if ((tid & 63) == 0) red[tid >> 6] = s;
        __syncthreads();
        if (tid == 0) {
            double tot = 0.0;
            for (int i = 0; i < 16; ++i) tot += red[i];
            perps[d] = (float)exp(-tot);
        }
        __syncthreads();
        if ((tid & 63) == 0) red[tid >> 6] = q;
        __syncthreads();
        if (tid == 0) {
            double tq = 0.0;
            for (int i = 0; i < 16; ++i) tq += red[i];
            lossAcc += tq;
        }
        __syncthreads();
    }
    if (tid == 0)
        loss[0] = (float)(1.25 * lossAcc / 8388608.0);
}

extern "C" void kernel_launch(void* const* d_in, const int* in_sizes, int n_in,
                              void* d_out, int out_size, void* d_ws, size_t ws_size,
                              hipStream_t stream)
{
    const float* z   = (const float*)d_in[0];
    const float* cbs = (const float*)d_in[1];
    float* out = (float*)d_out;
    char*  ws  = (char*)d_ws;

    int*            idxAll   = (int*)ws;
    int*            counts   = (int*)(ws + 393216);
    int*            flagcnt  = (int*)(ws + 405504);
    int*            flaglist = (int*)(ws + 405520);
    double*         ssepart  = (double*)(ws + 536592);
    float*          e2f      = (float*)(ws + 585744);
    unsigned short* cbp      = (unsigned short*)(ws + 598080);
    unsigned short* rp       = (unsigned short*)(ws + 3743808);
    float4*         partials = (float4*)(ws + 37298240);

    float* qtot  = out;                       // 8388608 elems
    float* loss  = out + 8388608;             // 1
    float* comp  = out + 8388609;             // 32768
    float* perps = out + 8388609 + 32768;     // 3

    // counts + flagcnt only (everything else is fully overwritten each launch)
    hipMemsetAsync(ws + 393216, 0, 405520 - 393216, stream);

    e2_kernel<<<12, 256, 0, stream>>>(cbs, e2f);
    pack_kernel<<<(3072 * 32) / 256, 256, 0, stream>>>(cbs, cbp);    // codebooks
    pack_kernel<<<(N_ROWS * 32) / 256, 256, 0, stream>>>(z, rp);     // stage-0 residual = z

    for (int d = 0; d < DEPTH; ++d) {
        const float* cb = cbs + (size_t)d * K * D;
        mfma_argmin_kernel<<<2048, 256, 0, stream>>>(
            cbp + (size_t)d * K * 512, rp, e2f + d * K, partials);
        merge_kernel<<<N_ROWS / 256, 256, 0, stream>>>(
            partials, idxAll + d * N_ROWS, flagcnt + d, flaglist);
        refine_kernel<<<128, 256, 0, stream>>>(
            z, qtot, cb, idxAll + d * N_ROWS, flagcnt + d, flaglist, d > 0 ? 1 : 0);
        fused_update_kernel<<<2048, 256, 0, stream>>>(
            z, qtot, cb, idxAll + d * N_ROWS, rp, counts + d * K,
            ssepart + d * 2048, d < DEPTH - 1 ? 1 : 0, d == 0 ? 1 : 0);
    }

    compose_kernel<<<(N_ROWS + 255) / 256, 256, 0, stream>>>(idxAll, comp);
    finalize_kernel<<<1, 1024, 0, stream>>>(counts, ssepart, loss, perps);
}

// Round 4
// 478.721 us; speedup vs baseline: 2.8120x; 1.1243x over previous
//
#include <hip/hip_runtime.h>
#include <math.h>

#define N_ROWS 32768
#define D 256
#define K 1024
#define DEPTH 3
#define MARGIN 0.05f

typedef __bf16 bf16x8 __attribute__((ext_vector_type(8)));
typedef float f32x4 __attribute__((ext_vector_type(4)));

// ---- ws layout (bytes) ----
// 0        idxAll[3][32768] int        -> 393216
// 393216   counts[3][1024] int         -> 405504
// 405504   flagcnt[3] int (pad to 405520)
// 405520   flaglist[32768] int         -> 536592
// 536592   ssepart[3][2048] double     -> 585744
// 585744   e2f[3][1024] float          -> 598032 (pad to 598080)
// 598080   cbp bf16 [3][1024][512]     -> 3743808
// 3743808  rp  bf16 [32768][512]       -> 37298240

__device__ __forceinline__ void gload_lds16(const void* g, void* l) {
    __builtin_amdgcn_global_load_lds(
        (const __attribute__((address_space(1))) void*)g,
        (__attribute__((address_space(3))) void*)l, 16, 0, 0);
}

__device__ __forceinline__ unsigned short f2bf(float f) {
    unsigned u = __float_as_uint(f);
    return (unsigned short)((u + 0x7fffu + ((u >> 16) & 1u)) >> 16);
}

// one wave per codebook row
__global__ __launch_bounds__(256) void e2_kernel(
    const float* __restrict__ cbs, float* __restrict__ e2f)
{
    int t = blockIdx.x * 256 + threadIdx.x;    // 768 blocks -> 3072 rows
    int row = t >> 6;
    int lane = t & 63;
    float4 v = *(const float4*)(cbs + (size_t)row * D + lane * 4);
    double s = (double)v.x * v.x + (double)v.y * v.y
             + (double)v.z * v.z + (double)v.w * v.w;
    for (int o = 32; o > 0; o >>= 1) s += __shfl_down(s, o, 64);
    if (lane == 0) e2f[row] = (float)s;
}

// Pack fp32 rows into [hi(256)|lo(256)] bf16 rows (stage-0 z pack and codebooks).
__global__ __launch_bounds__(256) void pack_kernel(
    const float* __restrict__ src, unsigned short* __restrict__ dst)
{
    int t = blockIdx.x * 256 + threadIdx.x;
    int row = t >> 5;
    int k8 = (t & 31) * 8;
    size_t off = (size_t)row * D + k8;
    float4 v0 = *(const float4*)(src + off);
    float4 v1 = *(const float4*)(src + off + 4);
    float v[8] = {v0.x, v0.y, v0.z, v0.w, v1.x, v1.y, v1.z, v1.w};
    typedef __attribute__((ext_vector_type(8))) unsigned short u16x8;
    u16x8 hv, lv;
    #pragma unroll
    for (int j = 0; j < 8; ++j) {
        ushort h = f2bf(v[j]);
        hv[j] = h;
        float hf = __uint_as_float(((unsigned)h) << 16);
        lv[j] = f2bf(v[j] - hf);
    }
    *(u16x8*)(dst + (size_t)row * 512 + k8) = hv;
    *(u16x8*)(dst + (size_t)row * 512 + 256 + k8) = lv;
}

// 64 rows resident in LDS (swizzled), loop all 8 code-chunks in-kernel.
// Writes final argmin + near-tie flags directly (no partials/merge pass).
__global__ __launch_bounds__(256, 2) void mfma_argmin_kernel(
    const unsigned short* __restrict__ cbp,   // [1024][512] packed bf16
    const unsigned short* __restrict__ rp,    // [32768][512] packed bf16
    const float* __restrict__ e2f,            // [1024]
    int* __restrict__ idxOut, int* __restrict__ flagcnt, int* __restrict__ flaglist)
{
    __shared__ __align__(16) __bf16 Bsm[64 * 512];   // 64 KB resident rows
    __shared__ __align__(16) __bf16 Asm[128 * 64];   // 16 KB code window

    const int tid = threadIdx.x;
    const int lane = tid & 63;
    const int w = tid >> 6;
    const int wm = w >> 1, wn = w & 1;     // wm: code half, wn: row half
    const int hi = lane >> 4;              // 0..3
    const int lo16 = lane & 15;
    const int row0 = blockIdx.x * 64;

    // ---- stage resident B rows (swizzled: linear dest, inverse-swz source) ----
    #pragma unroll
    for (int rr = 0; rr < 16; ++rr) {
        int q = rr * 256 + tid;            // 16B-chunk id, 4096 total
        int row = q >> 6;
        int lc = (q & 63) ^ (row & 7);
        gload_lds16(rp + (size_t)(row0 + row) * 512 + lc * 8, (char*)Bsm + q * 16);
    }

    // K=768 three-term split: A windows hi,lo,hi ; B windows hi,hi,lo (elems)
    constexpr int aO[12] = {0,64,128,192, 256,320,384,448, 0,64,128,192};
    constexpr int bO[12] = {0,64,128,192, 0,64,128,192, 256,320,384,448};

    float d1[2], d2[2];
    int   i1[2], i2[2];
    #pragma unroll
    for (int n = 0; n < 2; ++n) {
        d1[n] = 3.4e38f; d2[n] = 3.4e38f;
        i1[n] = 0x7fffffff; i2[n] = 0x7fffffff;
    }

    for (int cc = 0; cc < 8; ++cc) {
        const int cb0 = cc * 128;
        f32x4 acc[4][2];
        #pragma unroll
        for (int m = 0; m < 4; ++m)
            #pragma unroll
            for (int n = 0; n < 2; ++n)
                acc[m][n] = (f32x4){0.f, 0.f, 0.f, 0.f};

        #pragma unroll
        for (int s = 0; s < 12; ++s) {
            __syncthreads();               // prior window reads done (and B stage, first iter)
            #pragma unroll
            for (int rr = 0; rr < 4; ++rr) {
                int q = rr * 256 + tid;    // 16B-chunk id, 1024 total
                int code = q >> 3;
                int lc = (q & 7) ^ (code & 7);
                gload_lds16(cbp + (size_t)(cb0 + code) * 512 + aO[s] + lc * 8,
                            (char*)Asm + q * 16);
            }
            __syncthreads();               // drains vmcnt: window visible
            #pragma unroll
            for (int kk = 0; kk < 2; ++kk) {
                bf16x8 af[4], bfv[2];
                #pragma unroll
                for (int m = 0; m < 4; ++m) {
                    int cl = wm * 64 + m * 16 + lo16;
                    int lb = cl * 128 + kk * 64 + hi * 16;
                    af[m] = *(const bf16x8*)((const char*)Asm + (lb ^ ((cl & 7) << 4)));
                }
                #pragma unroll
                for (int n = 0; n < 2; ++n) {
                    int rw = wn * 32 + n * 16 + lo16;
                    int lb = rw * 1024 + bO[s] * 2 + kk * 64 + hi * 16;
                    bfv[n] = *(const bf16x8*)((const char*)Bsm + (lb ^ ((rw & 7) << 4)));
                }
                #pragma unroll
                for (int m = 0; m < 4; ++m)
                    #pragma unroll
                    for (int n = 0; n < 2; ++n)
                        acc[m][n] = __builtin_amdgcn_mfma_f32_16x16x32_bf16(
                            af[m], bfv[n], acc[m][n], 0, 0, 0);
            }
        }

        // epilogue: dist = e2 - 2*dot ; update per-lane top-2 (codes ascending)
        float e2a[4][4];
        #pragma unroll
        for (int m = 0; m < 4; ++m) {
            float4 t = *(const float4*)(e2f + cb0 + wm * 64 + m * 16 + hi * 4);
            e2a[m][0] = t.x; e2a[m][1] = t.y; e2a[m][2] = t.z; e2a[m][3] = t.w;
        }
        #pragma unroll
        for (int n = 0; n < 2; ++n)
            #pragma unroll
            for (int m = 0; m < 4; ++m)
                #pragma unroll
                for (int r = 0; r < 4; ++r) {
                    float dv = e2a[m][r] - 2.0f * acc[m][n][r];
                    int c = cb0 + wm * 64 + m * 16 + hi * 4 + r;
                    if (dv < d1[n])      { d2[n] = d1[n]; i2[n] = i1[n]; d1[n] = dv; i1[n] = c; }
                    else if (dv < d2[n]) { d2[n] = dv; i2[n] = c; }
                }
    }

    // butterfly merge across the 4 hi-groups (same rows, different codes)
    #pragma unroll
    for (int n = 0; n < 2; ++n) {
        #pragma unroll
        for (int mk = 0; mk < 2; ++mk) {
            int mask = mk ? 32 : 16;
            float od1 = __shfl_xor(d1[n], mask, 64);
            float od2 = __shfl_xor(d2[n], mask, 64);
            int   oi1 = __shfl_xor(i1[n], mask, 64);
            int   oi2 = __shfl_xor(i2[n], mask, 64);
            if (od1 < d1[n] || (od1 == d1[n] && oi1 < i1[n])) { d2[n] = d1[n]; i2[n] = i1[n]; d1[n] = od1; i1[n] = oi1; }
            else if (od1 < d2[n] || (od1 == d2[n] && oi1 < i2[n])) { d2[n] = od1; i2[n] = oi1; }
            if (od2 < d1[n] || (od2 == d1[n] && oi2 < i1[n])) { d2[n] = d1[n]; i2[n] = i1[n]; d1[n] = od2; i1[n] = oi2; }
            else if (od2 < d2[n] || (od2 == d2[n] && oi2 < i2[n])) { d2[n] = od2; i2[n] = oi2; }
        }
    }

    // cross-wm merge via LDS (Asm is dead now)
    float4* mb = (float4*)Asm;
    __syncthreads();
    if (lo16 == lane - hi * 16 && lane < 16) { /* lane<16 only */ }
    if (lane < 16) {
        #pragma unroll
        for (int n = 0; n < 2; ++n)
            mb[wm * 64 + wn * 32 + n * 16 + lo16] =
                make_float4(d1[n], d2[n], __int_as_float(i1[n]), __int_as_float(i2[n]));
    }
    __syncthreads();
    if (tid < 64) {
        float4 p = mb[tid];
        float4 q = mb[64 + tid];
        float fd1 = p.x, fd2 = p.y;
        int   fi1 = __float_as_int(p.z), fi2 = __float_as_int(p.w);
        float qd1 = q.x, qd2 = q.y;
        int   qi1 = __float_as_int(q.z), qi2 = __float_as_int(q.w);
        if (qd1 < fd1 || (qd1 == fd1 && qi1 < fi1)) { fd2 = fd1; fi2 = fi1; fd1 = qd1; fi1 = qi1; }
        else if (qd1 < fd2 || (qd1 == fd2 && qi1 < fi2)) { fd2 = qd1; fi2 = qi1; }
        if (qd2 < fd1 || (qd2 == fd1 && qi2 < fi1)) { fd2 = fd1; fi2 = fi1; fd1 = qd2; fi1 = qi2; }
        else if (qd2 < fd2 || (qd2 == fd2 && qi2 < fi2)) { fd2 = qd2; fi2 = qi2; }
        int row = row0 + tid;
        idxOut[row] = fi1;
        if (fd2 - fd1 < MARGIN) {
            int pos = atomicAdd(flagcnt, 1);
            if (pos < N_ROWS) flaglist[pos] = row;
        }
    }
}

// Exact fp64 re-rank for near-tie rows. residual = z - (useQ ? qtot : 0).
__global__ __launch_bounds__(256) void refine_kernel(
    const float* __restrict__ z, const float* __restrict__ qtot,
    const float* __restrict__ cb, int* __restrict__ idxOut,
    const int* __restrict__ flagcnt, const int* __restrict__ flaglist, int useQ)
{
    __shared__ double rres[D];
    __shared__ double bd[256];
    __shared__ int    bidx[256];
    const int tid = threadIdx.x;
    int cnt = *flagcnt;
    if (cnt > N_ROWS) cnt = N_ROWS;
    for (int f = blockIdx.x; f < cnt; f += gridDim.x) {
        int row = flaglist[f];
        __syncthreads();
        {
            float zv = z[(size_t)row * D + tid];
            float qv = useQ ? qtot[(size_t)row * D + tid] : 0.0f;
            rres[tid] = (double)(zv - qv);
        }
        __syncthreads();
        double best = 1e300; int bi = 0;
        for (int j = 0; j < 4; ++j) {
            int c = tid * 4 + j;
            const float* cp = cb + (size_t)c * D;
            double s = 0.0;
            for (int k = 0; k < D; ++k) {
                double df = rres[k] - (double)cp[k];
                s = fma(df, df, s);
            }
            if (s < best) { best = s; bi = c; }
        }
        bd[tid] = best; bidx[tid] = bi;
        __syncthreads();
        for (int off = 128; off > 0; off >>= 1) {
            if (tid < off) {
                if (bd[tid + off] < bd[tid] ||
                    (bd[tid + off] == bd[tid] && bidx[tid + off] < bidx[tid])) {
                    bd[tid] = bd[tid + off]; bidx[tid] = bidx[tid + off];
                }
            }
            __syncthreads();
        }
        if (tid == 0) idxOut[row] = bidx[0];
        __syncthreads();
    }
}

// Fused: qtot += cb[idx]; residual = z - qtot; pack residual (optional);
// SSE partial per block; counts. One pass over memory.
__global__ __launch_bounds__(256) void fused_update_kernel(
    const float* __restrict__ z, float* __restrict__ qtot,
    const float* __restrict__ cb, const int* __restrict__ idxStage,
    unsigned short* __restrict__ rpOut, int* __restrict__ counts,
    double* __restrict__ ssepart, int writeRp, int firstStage)
{
    double s = 0.0;
    const int base = blockIdx.x * 256 + threadIdx.x;
    #pragma unroll
    for (int it = 0; it < 4; ++it) {
        int t = base + it * 524288;            // quad id over N_ROWS*64
        int row = t >> 6;
        int c4  = (t & 63) << 2;
        int idx = idxStage[row];
        size_t off = (size_t)row * D + c4;
        float4 cv = *(const float4*)(cb + (size_t)idx * D + c4);
        float4 qv;
        if (firstStage) {
            qv = cv;
        } else {
            qv = *(const float4*)(qtot + off);
            qv.x += cv.x; qv.y += cv.y; qv.z += cv.z; qv.w += cv.w;
        }
        *(float4*)(qtot + off) = qv;
        float4 zv = *(const float4*)(z + off);
        float r0 = zv.x - qv.x, r1 = zv.y - qv.y;
        float r2 = zv.z - qv.z, r3 = zv.w - qv.w;
        s = fma((double)r0, (double)r0, s);
        s = fma((double)r1, (double)r1, s);
        s = fma((double)r2, (double)r2, s);
        s = fma((double)r3, (double)r3, s);
        if (writeRp) {
            float rv[4] = {r0, r1, r2, r3};
            ushort4 hv, lv;
            ushort* hp = (ushort*)&hv; ushort* lp = (ushort*)&lv;
            #pragma unroll
            for (int j = 0; j < 4; ++j) {
                ushort h = f2bf(rv[j]);
                hp[j] = h;
                float hf = __uint_as_float(((unsigned)h) << 16);
                lp[j] = f2bf(rv[j] - hf);
            }
            *(ushort4*)(rpOut + (size_t)row * 512 + c4) = hv;
            *(ushort4*)(rpOut + (size_t)row * 512 + 256 + c4) = lv;
        }
        if ((t & 63) == 0) atomicAdd(counts + idx, 1);
    }
    for (int o = 32; o > 0; o >>= 1) s += __shfl_down(s, o, 64);
    __shared__ double wsum[4];
    int lane = threadIdx.x & 63, wv = threadIdx.x >> 6;
    if (lane == 0) wsum[wv] = s;
    __syncthreads();
    if (threadIdx.x == 0)
        ssepart[blockIdx.x] = wsum[0] + wsum[1] + wsum[2] + wsum[3];
}

__global__ void compose_kernel(const int* __restrict__ idxAll, float* __restrict__ comp) {
    int n = blockIdx.x * 256 + threadIdx.x;
    if (n < N_ROWS) {
        int v = idxAll[n] + (idxAll[N_ROWS + n] << 10) + (idxAll[2 * N_ROWS + n] << 20);
        comp[n] = (float)v;
    }
}

__global__ void finalize_kernel(const int* __restrict__ counts, const double* __restrict__ ssepart,
                                float* __restrict__ loss, float* __restrict__ perps)
{
    __shared__ double red[16];
    __shared__ double lossAcc;
    const int tid = threadIdx.x;   // 1024 threads
    if (tid == 0) lossAcc = 0.0;
    __syncthreads();
    for (int d = 0; d < DEPTH; ++d) {
        double p = (double)counts[d * K + tid] / 32768.0;
        double s = p * log(p + 1e-10);
        double q = ssepart[d * 2048 + tid] + ssepart[d * 2048 + 1024 + tid];
        for (int o = 32; o > 0; o >>= 1) {
            s += __shfl_down(s, o, 64);
            q += __shfl_down(q, o, 64);
        }
        if ((tid & 63) == 0) red[tid >> 6] = s;
        __syncthreads();
        if (tid == 0) {
            double tot = 0.0;
            for (int i = 0; i < 16; ++i) tot += red[i];
            perps[d] = (float)exp(-tot);
        }
        __syncthreads();
        if ((tid & 63) == 0) red[tid >> 6] = q;
        __syncthreads();
        if (tid == 0) {
            double tq = 0.0;
            for (int i = 0; i < 16; ++i) tq += red[i];
            lossAcc += tq;
        }
        __syncthreads();
    }
    if (tid == 0)
        loss[0] = (float)(1.25 * lossAcc / 8388608.0);
}

extern "C" void kernel_launch(void* const* d_in, const int* in_sizes, int n_in,
                              void* d_out, int out_size, void* d_ws, size_t ws_size,
                              hipStream_t stream)
{
    const float* z   = (const float*)d_in[0];
    const float* cbs = (const float*)d_in[1];
    float* out = (float*)d_out;
    char*  ws  = (char*)d_ws;

    int*            idxAll   = (int*)ws;
    int*            counts   = (int*)(ws + 393216);
    int*            flagcnt  = (int*)(ws + 405504);
    int*            flaglist = (int*)(ws + 405520);
    double*         ssepart  = (double*)(ws + 536592);
    float*          e2f      = (float*)(ws + 585744);
    unsigned short* cbp      = (unsigned short*)(ws + 598080);
    unsigned short* rp       = (unsigned short*)(ws + 3743808);

    float* qtot  = out;                       // 8388608 elems
    float* loss  = out + 8388608;             // 1
    float* comp  = out + 8388609;             // 32768
    float* perps = out + 8388609 + 32768;     // 3

    hipMemsetAsync(ws + 393216, 0, 405520 - 393216, stream);  // counts + flagcnt

    e2_kernel<<<768, 256, 0, stream>>>(cbs, e2f);
    pack_kernel<<<(3072 * 32) / 256, 256, 0, stream>>>(cbs, cbp);    // codebooks
    pack_kernel<<<(N_ROWS * 32) / 256, 256, 0, stream>>>(z, rp);     // stage-0 residual = z

    for (int d = 0; d < DEPTH; ++d) {
        const float* cb = cbs + (size_t)d * K * D;
        mfma_argmin_kernel<<<512, 256, 0, stream>>>(
            cbp + (size_t)d * K * 512, rp, e2f + d * K,
            idxAll + d * N_ROWS, flagcnt + d, flaglist);
        refine_kernel<<<128, 256, 0, stream>>>(
            z, qtot, cb, idxAll + d * N_ROWS, flagcnt + d, flaglist, d > 0 ? 1 : 0);
        fused_update_kernel<<<2048, 256, 0, stream>>>(
            z, qtot, cb, idxAll + d * N_ROWS, rp, counts + d * K,
            ssepart + d * 2048, d < DEPTH - 1 ? 1 : 0, d == 0 ? 1 : 0);
    }

    compose_kernel<<<(N_ROWS + 255) / 256, 256, 0, stream>>>(idxAll, comp);
    finalize_kernel<<<1, 1024, 0, stream>>>(counts, ssepart, loss, perps);
}